// Round 7
// baseline (1341.618 us; speedup 1.0000x reference)
//
#include <hip/hip_runtime.h>

// BatchedMonomialFactor round 7 (= round 6 with two fixes):
//  - FIX: k_w2gemm LDS was 32768 B but B staging needs bytes 16384..49152 ->
//    WAS fragments read garbage -> g corrupted (absmax 1.55). Now 49152 B.
//  - FIX: sinkhorn max-subtraction restored (exact R4-proven base-2 path);
//    removing it was an unproven ~1e-6-class perturbation.
//  - Numerics: proven 6-product bf16x3 perm GEMM; diag/alpha in separate
//    3-product bf16x2 kernel writing g=sigmoid(A)*tanh(D).
//  - Structure: 128x256 main tile, BK=32, A+B staged via global_load_lds with
//    k-major ws layouts (contiguous 1KB per DMA), 192 MFMA/wave per barrier
//    pair, acc-only AGPR (128) -> no spill, XCD swizzle.

#define XSZ 2097152                    // 2048*1024 elems per plane
#define WPSZ 16777216                  // per plane
#define WDSZ 1048576                   // per plane

#define OFF_XS   0u
#define OFF_WPS  12582912u             // 3*XSZ*2
#define OFF_WDS  113246208u            // OFF_WPS + 3*WPSZ*2
#define OFF_WAS  117440512u            // OFF_WDS + 2*WDSZ*2
#define OFF_GV   121634816u            // OFF_WAS + 2*WDSZ*2
#define WS_NEED  130023424u            // OFF_GV + 8MB (== proven R2 value)

#define LSCALE 2.8853900817779268f     // (1/TAU=2)*log2(e)

typedef __attribute__((ext_vector_type(8))) short short8;
typedef __attribute__((ext_vector_type(4))) float f32x4;
#define MFMA_BF16 __builtin_amdgcn_mfma_f32_16x16x32_bf16

#define GLOAD_LDS16(g, lp) __builtin_amdgcn_global_load_lds( \
    (const __attribute__((address_space(1))) unsigned int*)(g), \
    (__attribute__((address_space(3))) unsigned int*)(lp), 16, 0, 0)

__device__ __forceinline__ unsigned short f2bf_rne(float f) {
    unsigned u = __float_as_uint(f);
    unsigned r = (u + 0x7fffu + ((u >> 16) & 1u)) >> 16;
    return (unsigned short)r;
}
__device__ __forceinline__ float bf2f(unsigned short s) {
    return __uint_as_float(((unsigned)s) << 16);
}

// ---- prep: x -> XS[p][oct=ks*4+kq][b][8j]  (coalesced 16B/lane writes) ----
__global__ void k_split_x(const float* __restrict__ x, unsigned short* __restrict__ XS) {
    const int oct = blockIdx.x;                 // 0..127
    const int b   = blockIdx.y * 256 + threadIdx.x;
    const float* src = x + (long)b * 1024 + oct * 8;
    const float4 v0 = *(const float4*)src;
    const float4 v1 = *(const float4*)(src + 4);
    const float vv[8] = {v0.x, v0.y, v0.z, v0.w, v1.x, v1.y, v1.z, v1.w};
    short8 o1, o2, o3;
    #pragma unroll
    for (int j = 0; j < 8; j++) {
        const unsigned short s1 = f2bf_rne(vv[j]);
        const float r1 = vv[j] - bf2f(s1);
        const unsigned short s2 = f2bf_rne(r1);
        o1[j] = (short)s1; o2[j] = (short)s2; o3[j] = (short)f2bf_rne(r1 - bf2f(s2));
    }
    const long off = ((long)oct * 2048 + b) * 8;
    *(short8*)(XS + off) = o1;
    *(short8*)(XS + XSZ + off) = o2;
    *(short8*)(XS + 2 * (long)XSZ + off) = o3;
}

// ---- prep: Wp[k][c] -> WPS[p][r][ks][kq][n][8j] ---------------------------
__global__ void k_split_w(const float* __restrict__ W, unsigned short* __restrict__ dst) {
    __shared__ float tile[32][260];
    const int t = threadIdx.x;
    const int r = blockIdx.x, ks = blockIdx.y;
    #pragma unroll
    for (int e = 0; e < 8; e++) {
        const int id = t + 256 * e;
        const int k = id >> 6, n4 = (id & 63) * 4;
        *(float4*)&tile[k][n4] = *(const float4*)(W + ((long)ks * 32 + k) * 16384 + r * 256 + n4);
    }
    __syncthreads();
    #pragma unroll
    for (int e = 0; e < 4; e++) {
        const int id = t + 256 * e;                 // 0..1023
        const int kq = id >> 8, n = id & 255;
        short8 o1, o2, o3;
        #pragma unroll
        for (int j = 0; j < 8; j++) {
            const float v = tile[kq * 8 + j][n];
            const unsigned short s1 = f2bf_rne(v);
            const float r1 = v - bf2f(s1);
            const unsigned short s2 = f2bf_rne(r1);
            o1[j] = (short)s1; o2[j] = (short)s2; o3[j] = (short)f2bf_rne(r1 - bf2f(s2));
        }
        const long off = ((((long)r * 32 + ks) * 4 + kq) * 256 + n) * 8;
        *(short8*)(dst + off) = o1;
        *(short8*)(dst + WPSZ + off) = o2;
        *(short8*)(dst + 2 * (long)WPSZ + off) = o3;
    }
}

// ---- prep: Wd/Wa -> [p][r][ks][kq][n16][8j], 2 planes ---------------------
__global__ void k_split_w2(const float* __restrict__ Wd, const float* __restrict__ Wa,
                           unsigned short* __restrict__ WDS_, unsigned short* __restrict__ WAS_) {
    __shared__ float tile[32][68];
    const float* W = blockIdx.z ? Wa : Wd;
    unsigned short* dst = blockIdx.z ? WAS_ : WDS_;
    const int t = threadIdx.x;
    const int c0 = blockIdx.x * 64, ks = blockIdx.y;
    #pragma unroll
    for (int e = 0; e < 2; e++) {
        const int id = t + 256 * e;                 // 0..511
        const int k = id >> 4, n4 = (id & 15) * 4;
        *(float4*)&tile[k][n4] = *(const float4*)(W + ((long)ks * 32 + k) * 1024 + c0 + n4);
    }
    __syncthreads();
    const int kq = t >> 6, cl = t & 63;
    const int c = c0 + cl;
    const int rr = c >> 4, nn = c & 15;
    short8 o1, o2;
    #pragma unroll
    for (int j = 0; j < 8; j++) {
        const float v = tile[kq * 8 + j][cl];
        const unsigned short s1 = f2bf_rne(v);
        o1[j] = (short)s1;
        o2[j] = (short)f2bf_rne(v - bf2f(s1));
    }
    const int off = (((rr * 32 + ks) * 4 + kq) * 16 + nn) * 8;
    *(short8*)(dst + off) = o1;
    *(short8*)(dst + WDSZ + off) = o2;
}

// ---- diag/alpha GEMM: g = sigmoid(x@Wa) * tanh(x@Wd), bf16x2 3-product ----
__global__ __launch_bounds__(256, 2)
void k_w2gemm(const unsigned short* __restrict__ XS,
              const unsigned short* __restrict__ WDS,
              const unsigned short* __restrict__ WAS,
              float* __restrict__ GV)
{
    __shared__ __align__(16) char smc[49152];   // A 16KB | B 32KB  (was 32KB: OOB bug)
    const int t = threadIdx.x;
    const int l = t & 63, w = t >> 6;
    const int bt = blockIdx.x & 15, ct = blockIdx.x >> 4;   // 16 x 8
    const int b0 = bt * 128, c0 = ct * 128;
    const int quad = l >> 4, l15 = l & 15;
    const int rt0 = c0 >> 4;

    f32x4 accD[8][2], accA[8][2];
    #pragma unroll
    for (int a = 0; a < 8; a++)
        #pragma unroll
        for (int b = 0; b < 2; b++) {
            accD[a][b] = (f32x4){0.f, 0.f, 0.f, 0.f};
            accA[a][b] = (f32x4){0.f, 0.f, 0.f, 0.f};
        }

    for (int ks = 0; ks < 32; ++ks) {
        // stage: A slots 0..15 (2p x 4kq x 2hf), B slots 16..47 (2src x 2p x 8rt)
        #pragma unroll
        for (int e = 0; e < 12; e++) {
            const int slot = w * 12 + e;
            if (slot < 16) {
                const int p = slot >> 3, kq = (slot >> 1) & 3, hf = slot & 1;
                const unsigned short* g = XS + (long)p * XSZ + (((long)ks * 4 + kq) * 2048 + b0 + hf * 64 + l) * 8;
                GLOAD_LDS16(g, smc + ((p * 4 + kq) * 128 + hf * 64) * 16);
            } else {
                const int s2 = slot - 16;
                const int src = s2 >> 4, p = (s2 >> 3) & 1, rt = s2 & 7;
                const unsigned short* base = (src ? WAS : WDS) + (long)p * WDSZ
                    + ((long)(rt0 + rt) * 32 + ks) * 512 + l * 8;
                GLOAD_LDS16(base, smc + 16384 + ((src * 2 + p) * 8 + rt) * 1024);
            }
        }
        __syncthreads();
        short8 bD[2][2], bA[2][2];
        #pragma unroll
        for (int p = 0; p < 2; p++)
            #pragma unroll
            for (int nt = 0; nt < 2; nt++) {
                const int rt = 2 * w + nt;
                bD[p][nt] = *(const short8*)(smc + 16384 + ((0 * 2 + p) * 8 + rt) * 1024 + quad * 256 + l15 * 16);
                bA[p][nt] = *(const short8*)(smc + 16384 + ((1 * 2 + p) * 8 + rt) * 1024 + quad * 256 + l15 * 16);
            }
        #pragma unroll
        for (int mt = 0; mt < 8; mt++) {
            const int ro = (mt * 16 + l15) * 16;
            const short8 a0 = *(const short8*)(smc + ((0 * 4 + quad) * 128) * 16 + ro);
            const short8 a1 = *(const short8*)(smc + ((1 * 4 + quad) * 128) * 16 + ro);
            #pragma unroll
            for (int nt = 0; nt < 2; nt++) {
                f32x4 c = accD[mt][nt];
                c = MFMA_BF16(a0, bD[0][nt], c, 0, 0, 0);
                c = MFMA_BF16(a0, bD[1][nt], c, 0, 0, 0);
                c = MFMA_BF16(a1, bD[0][nt], c, 0, 0, 0);
                accD[mt][nt] = c;
                f32x4 d = accA[mt][nt];
                d = MFMA_BF16(a0, bA[0][nt], d, 0, 0, 0);
                d = MFMA_BF16(a0, bA[1][nt], d, 0, 0, 0);
                d = MFMA_BF16(a1, bA[0][nt], d, 0, 0, 0);
                accA[mt][nt] = d;
            }
        }
        __syncthreads();
    }
    #pragma unroll
    for (int mt = 0; mt < 8; mt++)
        #pragma unroll
        for (int nt = 0; nt < 2; nt++)
            #pragma unroll
            for (int q = 0; q < 4; q++) {
                const int row = b0 + mt * 16 + quad * 4 + q;
                const int c = c0 + (2 * w + nt) * 16 + l15;
                const float sg = 1.0f / (1.0f + expf(-accA[mt][nt][q]));
                GV[(long)row * 1024 + c] = sg * tanhf(accD[mt][nt][q]);
            }
}

// ---------------- main fused kernel: perm GEMM + sinkhorn + combine ---------
__global__ __launch_bounds__(256, 2)
void bmf_main(const unsigned short* __restrict__ XS,
              const unsigned short* __restrict__ WPS,
              const float* __restrict__ GV,
              const float* __restrict__ h,
              float* __restrict__ out)
{
    // GEMM: A [3p][4kq][128 rows]x16B = 24576 | B [3p][4kq][256 n]x16B = 49152
    // epilogue aliases: la [32][272]f | hv 2048f | hpm 2048f (51200 B)
    __shared__ __align__(16) char smc[73728];
    float* la  = (float*)smc;
    float* hv  = (float*)smc + 8704;
    float* hpm = (float*)smc + 10752;

    const int t = threadIdx.x;
    const int l = t & 63, w = t >> 6;
    const int bid = blockIdx.x;                 // 1024 blocks
    // XCD swizzle: bid&7 = XCD gets 16 bt of one r
    const int r  = ((bid >> 7) << 3) | (bid & 7);
    const int bt = (bid >> 3) & 15;
    const int b0 = bt * 128;
    const int quad = l >> 4, l15 = l & 15;

    f32x4 acc[8][4];
    #pragma unroll
    for (int a = 0; a < 8; a++)
        #pragma unroll
        for (int b = 0; b < 4; b++) acc[a][b] = (f32x4){0.f, 0.f, 0.f, 0.f};

    for (int ks = 0; ks < 32; ++ks) {
        // stage 72 slots: A 0..23 (3p x 4kq x 2hf), B 24..71 (3p x 4kq x 4ng)
        #pragma unroll
        for (int e = 0; e < 18; e++) {
            const int slot = w * 18 + e;
            if (slot < 24) {
                const int p = slot >> 3, kq = (slot >> 1) & 3, hf = slot & 1;
                const unsigned short* g = XS + (long)p * XSZ + (((long)ks * 4 + kq) * 2048 + b0 + hf * 64 + l) * 8;
                GLOAD_LDS16(g, smc + ((p * 4 + kq) * 128 + hf * 64) * 16);
            } else {
                const int s2 = slot - 24;
                const int p = s2 >> 4, kq = (s2 >> 2) & 3, ng = s2 & 3;
                const unsigned short* g = WPS + (long)p * WPSZ + ((((long)r * 32 + ks) * 4 + kq) * 256 + ng * 64 + l) * 8;
                GLOAD_LDS16(g, smc + 24576 + ((p * 4 + kq) * 256 + ng * 64) * 16);
            }
        }
        __syncthreads();
        short8 bf[3][4];
        #pragma unroll
        for (int p = 0; p < 3; p++)
            #pragma unroll
            for (int nt = 0; nt < 4; nt++)
                bf[p][nt] = *(const short8*)(smc + 24576 + ((p * 4 + quad) * 256 + (w * 4 + nt) * 16 + l15) * 16);
        #pragma unroll
        for (int mt = 0; mt < 8; mt++) {
            const int ro = (mt * 16 + l15) * 16;
            const short8 a0 = *(const short8*)(smc + ((0 * 4 + quad) * 128) * 16 + ro);
            const short8 a1 = *(const short8*)(smc + ((1 * 4 + quad) * 128) * 16 + ro);
            const short8 a2 = *(const short8*)(smc + ((2 * 4 + quad) * 128) * 16 + ro);
            #pragma unroll
            for (int nt = 0; nt < 4; nt++) {
                f32x4 c = acc[mt][nt];
                c = MFMA_BF16(a0, bf[0][nt], c, 0, 0, 0);
                c = MFMA_BF16(a0, bf[1][nt], c, 0, 0, 0);
                c = MFMA_BF16(a1, bf[0][nt], c, 0, 0, 0);
                c = MFMA_BF16(a0, bf[2][nt], c, 0, 0, 0);
                c = MFMA_BF16(a1, bf[1][nt], c, 0, 0, 0);
                c = MFMA_BF16(a2, bf[0][nt], c, 0, 0, 0);
                acc[mt][nt] = c;
            }
        }
        __syncthreads();
    }

    // ---- stage h, zero hpm (128 rows x 16) ----
    #pragma unroll
    for (int q = 0; q < 8; q++) {
        const int id = t + 256 * q;
        const int row = id >> 4, j = id & 15;
        hv[id]  = h[(long)(b0 + row) * 1024 + r * 16 + j];
        hpm[id] = 0.f;
    }
    __syncthreads();

    // ---- sinkhorn (base-2, max-sub: R4-proven) + argmax + scatter ----------
    for (int ch = 0; ch < 4; ++ch) {
        #pragma unroll
        for (int mi = 0; mi < 2; mi++) {
            const int mt = ch * 2 + mi;
            #pragma unroll
            for (int nt = 0; nt < 4; nt++)
                #pragma unroll
                for (int q = 0; q < 4; q++) {
                    const int ml = mi * 16 + quad * 4 + q;
                    la[ml * 272 + (w * 4 + nt) * 17 + l15] = acc[mt][nt][q] * LSCALE;
                }
        }
        __syncthreads();
        for (int it = 0; it < 5; ++it) {
            #pragma unroll
            for (int q = 0; q < 2; q++) {
                const int id = t + 256 * q;
                const int m = id >> 4, i = id & 15;
                float* rowp = la + m * 272 + i * 17;
                float mx = rowp[0];
                #pragma unroll
                for (int j = 1; j < 16; j++) mx = fmaxf(mx, rowp[j]);
                float s = 0.f;
                #pragma unroll
                for (int j = 0; j < 16; j++) s += exp2f(rowp[j] - mx);
                const float lse = mx + log2f(s);
                #pragma unroll
                for (int j = 0; j < 16; j++) rowp[j] -= lse;
            }
            __syncthreads();
            #pragma unroll
            for (int q = 0; q < 2; q++) {
                const int id = t + 256 * q;
                const int m = id >> 4, j = id & 15;
                float* colp = la + m * 272 + j;
                float mx = colp[0];
                #pragma unroll
                for (int i = 1; i < 16; i++) mx = fmaxf(mx, colp[i * 17]);
                float s = 0.f;
                #pragma unroll
                for (int i = 0; i < 16; i++) s += exp2f(colp[i * 17] - mx);
                const float lse = mx + log2f(s);
                #pragma unroll
                for (int i = 0; i < 16; i++) colp[i * 17] -= lse;
            }
            __syncthreads();
        }
        #pragma unroll
        for (int q = 0; q < 2; q++) {
            const int id = t + 256 * q;
            const int m = id >> 4, j = id & 15;
            const float* colp = la + m * 272 + j;
            float best = colp[0]; int bi = 0;
            #pragma unroll
            for (int i = 1; i < 16; i++) {
                const float v = colp[i * 17];
                if (v > best) { best = v; bi = i; }
            }
            const int gm = ch * 32 + m;
            atomicAdd(&hpm[gm * 16 + bi], hv[gm * 16 + j]);
        }
        __syncthreads();
    }

    // ---- final: out = g * h_permuted ----
    #pragma unroll
    for (int q = 0; q < 8; q++) {
        const int id = t + 256 * q;
        const int row = id >> 4, i = id & 15;
        const float g = GV[(long)(b0 + row) * 1024 + r * 16 + i];
        out[(long)(b0 + row) * 1024 + r * 16 + i] = g * hpm[id];
    }
}

// ---------------- fallback: round-1 fp32 kernel ----------------------------
__global__ __launch_bounds__(256, 2)
void bmf_fused_kernel(const float* __restrict__ x,
                      const float* __restrict__ h,
                      const float* __restrict__ Wp,
                      const float* __restrict__ Wd,
                      const float* __restrict__ Wa,
                      float* __restrict__ out)
{
    __shared__ float sm[15488];
    float* xs   = sm;
    float* wsh  = sm + 32 * 68;
    float* w2s  = wsh + 32 * 256;
    float* la   = sm;
    float* dval = sm + 11392;
    float* aval = dval + 1024;
    float* hv   = aval + 1024;
    float* hpm  = hv + 1024;

    const int t   = threadIdx.x;
    const int bid = blockIdx.x;
    const int r   = bid >> 5;
    const int b0  = (bid & 31) * 64;
    const long rcol0 = (long)r * 256;
    const int tr  = t >> 5;
    const int tc  = t & 31;
    const int cAi = tc * 4;
    const int cBi = 128 + tc * 4;
    const int row2 = t >> 2;
    const int c2   = (t & 3) * 8;

    float acc[8][8];
    float acc2[8];
    #pragma unroll
    for (int i = 0; i < 8; i++) {
        acc2[i] = 0.f;
        #pragma unroll
        for (int j = 0; j < 8; j++) acc[i][j] = 0.f;
    }
    for (int ks = 0; ks < 32; ++ks) {
        const int k0 = ks * 32;
        {
            const int row = t >> 2, kq = t & 3;
            #pragma unroll
            for (int e = 0; e < 2; e++) {
                const int kk = kq * 4 + e * 16;
                const float4 g = *(const float4*)(x + (long)(b0 + row) * 1024 + k0 + kk);
                xs[(kk + 0) * 68 + row] = g.x;
                xs[(kk + 1) * 68 + row] = g.y;
                xs[(kk + 2) * 68 + row] = g.z;
                xs[(kk + 3) * 68 + row] = g.w;
            }
        }
        {
            const int rbase = t >> 6;
            const int colf  = (t & 63) * 4;
            #pragma unroll
            for (int rep = 0; rep < 8; rep++) {
                const int rowk = rbase + rep * 4;
                const float4 g = *(const float4*)(Wp + (long)(k0 + rowk) * 16384 + rcol0 + colf);
                *(float4*)(wsh + rowk * 256 + colf) = g;
            }
        }
        {
            const int kr = t >> 3;
            const int c  = (t & 7) * 4;
            const float* src = (c < 16)
                ? (Wd + (long)(k0 + kr) * 1024 + r * 16 + c)
                : (Wa + (long)(k0 + kr) * 1024 + r * 16 + (c - 16));
            *(float4*)(w2s + kr * 32 + c) = *(const float4*)src;
        }
        __syncthreads();
        #pragma unroll
        for (int kk = 0; kk < 32; ++kk) {
            const float4 xlo = *(const float4*)(xs + kk * 68 + tr * 8);
            const float4 xhi = *(const float4*)(xs + kk * 68 + tr * 8 + 4);
            const float4 wA  = *(const float4*)(wsh + kk * 256 + cAi);
            const float4 wB  = *(const float4*)(wsh + kk * 256 + cBi);
            const float xv[8] = {xlo.x, xlo.y, xlo.z, xlo.w, xhi.x, xhi.y, xhi.z, xhi.w};
            #pragma unroll
            for (int ri = 0; ri < 8; ri++) {
                acc[ri][0] += xv[ri] * wA.x; acc[ri][1] += xv[ri] * wA.y;
                acc[ri][2] += xv[ri] * wA.z; acc[ri][3] += xv[ri] * wA.w;
                acc[ri][4] += xv[ri] * wB.x; acc[ri][5] += xv[ri] * wB.y;
                acc[ri][6] += xv[ri] * wB.z; acc[ri][7] += xv[ri] * wB.w;
            }
            const float xv2 = xs[kk * 68 + row2];
            const float4 u0 = *(const float4*)(w2s + kk * 32 + c2);
            const float4 u1 = *(const float4*)(w2s + kk * 32 + c2 + 4);
            acc2[0] += xv2 * u0.x; acc2[1] += xv2 * u0.y;
            acc2[2] += xv2 * u0.z; acc2[3] += xv2 * u0.w;
            acc2[4] += xv2 * u1.x; acc2[5] += xv2 * u1.y;
            acc2[6] += xv2 * u1.z; acc2[7] += xv2 * u1.w;
        }
        __syncthreads();
    }
    #pragma unroll
    for (int e = 0; e < 8; e++) {
        const int c = c2 + e;
        if (c < 16) dval[row2 * 16 + c] = acc2[e];
        else        aval[row2 * 16 + (c - 16)] = acc2[e];
    }
    #pragma unroll
    for (int q = 0; q < 4; q++) {
        const int id  = t + 256 * q;
        const int row = id >> 4, j = id & 15;
        hv[id]  = h[(long)(b0 + row) * 1024 + r * 16 + j];
        hpm[id] = 0.f;
    }
    __syncthreads();
    for (int half = 0; half < 2; ++half) {
        if ((tr >> 2) == half) {
            const int mbase = (tr & 3) * 8;
            #pragma unroll
            for (int ri = 0; ri < 8; ri++) {
                const int m = mbase + ri;
                #pragma unroll
                for (int e = 0; e < 8; e++) {
                    const int col = (e < 4) ? (cAi + e) : (cBi + e - 4);
                    la[m * 272 + (col >> 4) * 17 + (col & 15)] = acc[ri][e] * 2.0f;
                }
            }
        }
        __syncthreads();
        for (int it = 0; it < 5; ++it) {
            #pragma unroll
            for (int q = 0; q < 2; q++) {
                const int id = t + 256 * q;
                const int m = id >> 4, i = id & 15;
                float* rowp = la + m * 272 + i * 17;
                float mx = rowp[0];
                #pragma unroll
                for (int j = 1; j < 16; j++) mx = fmaxf(mx, rowp[j]);
                float s = 0.f;
                #pragma unroll
                for (int j = 0; j < 16; j++) s += expf(rowp[j] - mx);
                const float lse = mx + logf(s);
                #pragma unroll
                for (int j = 0; j < 16; j++) rowp[j] -= lse;
            }
            __syncthreads();
            #pragma unroll
            for (int q = 0; q < 2; q++) {
                const int id = t + 256 * q;
                const int m = id >> 4, j = id & 15;
                float* colp = la + m * 272 + j;
                float mx = colp[0];
                #pragma unroll
                for (int i = 1; i < 16; i++) mx = fmaxf(mx, colp[i * 17]);
                float s = 0.f;
                #pragma unroll
                for (int i = 0; i < 16; i++) s += expf(colp[i * 17] - mx);
                const float lse = mx + logf(s);
                #pragma unroll
                for (int i = 0; i < 16; i++) colp[i * 17] -= lse;
            }
            __syncthreads();
        }
        #pragma unroll
        for (int q = 0; q < 2; q++) {
            const int id = t + 256 * q;
            const int m = id >> 4, j = id & 15;
            const float* colp = la + m * 272 + j;
            float best = colp[0]; int bi = 0;
            #pragma unroll
            for (int i = 1; i < 16; i++) {
                const float v = colp[i * 17];
                if (v > best) { best = v; bi = i; }
            }
            const int gm = half * 32 + m;
            atomicAdd(&hpm[gm * 16 + bi], hv[gm * 16 + j]);
        }
        __syncthreads();
    }
    #pragma unroll
    for (int q = 0; q < 4; q++) {
        const int id  = t + 256 * q;
        const int row = id >> 4, i = id & 15;
        const float A  = aval[id];
        const float Dv = dval[id];
        const float sg = 1.0f / (1.0f + expf(-A));
        out[(long)(b0 + row) * 1024 + r * 16 + i] = sg * tanhf(Dv) * hpm[id];
    }
}

extern "C" void kernel_launch(void* const* d_in, const int* in_sizes, int n_in,
                              void* d_out, int out_size, void* d_ws, size_t ws_size,
                              hipStream_t stream) {
    const float* x  = (const float*)d_in[0];
    const float* h  = (const float*)d_in[1];
    const float* Wp = (const float*)d_in[2];
    const float* Wd = (const float*)d_in[3];
    const float* Wa = (const float*)d_in[4];
    float* out = (float*)d_out;

    if (ws_size >= (size_t)WS_NEED) {
        unsigned short* XS  = (unsigned short*)((char*)d_ws + OFF_XS);
        unsigned short* WPS = (unsigned short*)((char*)d_ws + OFF_WPS);
        unsigned short* WDS = (unsigned short*)((char*)d_ws + OFF_WDS);
        unsigned short* WAS = (unsigned short*)((char*)d_ws + OFF_WAS);
        float*          GV  = (float*)((char*)d_ws + OFF_GV);
        k_split_x<<<dim3(128, 8), dim3(256), 0, stream>>>(x, XS);
        k_split_w<<<dim3(64, 32), dim3(256), 0, stream>>>(Wp, WPS);
        k_split_w2<<<dim3(16, 32, 2), dim3(256), 0, stream>>>(Wd, Wa, WDS, WAS);
        k_w2gemm<<<dim3(128), dim3(256), 0, stream>>>(XS, WDS, WAS, GV);
        bmf_main<<<dim3(1024), dim3(256), 0, stream>>>(XS, WPS, GV, h, out);
    } else {
        bmf_fused_kernel<<<dim3(2048), dim3(256), 0, stream>>>(x, h, Wp, Wd, Wa, out);
    }
}